// Round 8
// baseline (16.946 us; speedup 1.0000x reference)
//
#include <hip/hip_runtime.h>

// SvmLoss N=8192, RANK_RATIO=1.0 -> out = rank_loss (scalar f32).
// rank_loss = sum_{i,j} [t_i<t_j && status_i==1] * max(1+logit_j-logit_i,0)^2
//             / max(#pairs,1)
//
// R8: established structure: two kernel nodes (fused atomic tails cost
// +10..20us, R2/R3/R6), wave-ballot compaction of status-1 rows (R7, -2us),
// packed-f32 hinge math, per-lane v_addc counts.
// New: BLK=1024/GRID=256 (same 4 waves/SIMD, 4x fewer block pro/epilogues),
// packed (sum,cnt) uint2 partial -> single dwordx2 store, 1-wave final kernel
// (no LDS, no barriers). Calibrated fixed 2-node graph overhead ~14.5us;
// loop ~2us. This trims the last non-overhead cycles.

typedef float f32x2 __attribute__((ext_vector_type(2)));

constexpr int N_   = 8192;
constexpr int BLK  = 1024;            // 16 waves/block
constexpr int R    = 4;               // j columns per lane
constexpr int JPB  = BLK * R;         // 4096 j per block
constexpr int NJB  = N_ / JPB;        // 2 j-blocks
constexpr int ICH  = 64;              // i per chunk (= one wave for compaction)
constexpr int NIC  = N_ / ICH;        // 128 i-chunks
constexpr int GRID = NJB * NIC;       // 256 blocks = 1/CU, 4 waves/SIMD

__global__ __launch_bounds__(BLK) void svm_partial(
        const float* __restrict__ logit,
        const float* __restrict__ st,      // [N][2] status,time
        uint2* __restrict__ part) {        // (f32bits(sum), cnt)
    __shared__ float2 ci_s[ICH];          // compacted (logit_i, time_i)
    __shared__ int    total_s;
    __shared__ float  wsum[BLK / 64];
    __shared__ int    wcnt[BLK / 64];

    const int jb = (int)blockIdx.x & (NJB - 1);
    const int ic = (int)blockIdx.x / NJB;
    const int j0 = jb * JPB + (int)threadIdx.x * R;   // 16B-aligned

    const float4 lj4 = *(const float4*)(logit + j0);
    const float4 sa  = *(const float4*)(st + 2 * j0);      // (s,t) j0,j0+1
    const float4 sb  = *(const float4*)(st + 2 * j0 + 4);  // (s,t) j0+2,j0+3
    // x = li - (1+lj); hinge^2 = min(x,0)^2
    const f32x2 nljpA = { -(1.0f + lj4.x), -(1.0f + lj4.y) };
    const f32x2 nljpB = { -(1.0f + lj4.z), -(1.0f + lj4.w) };
    const float tj0 = sa.y, tj1 = sa.w, tj2 = sb.y, tj3 = sb.w;

    // Wave 0 compacts the chunk's status-1 rows into LDS (deterministic order)
    if (threadIdx.x < 64) {
        const int    i    = ic * ICH + (int)threadIdx.x;
        const float  li   = logit[i];
        const float2 sv   = *(const float2*)(st + 2 * i);
        const bool   keep = (sv.x == 1.0f);
        const unsigned long long mk = __ballot(keep);
        const int pos = (int)__popcll(mk & ((1ull << threadIdx.x) - 1ull));
        if (keep) ci_s[pos] = make_float2(li, sv.y);
        if (threadIdx.x == 0) total_s = (int)__popcll(mk);
    }
    __syncthreads();
    const int total = total_s;            // wave-uniform loop bound

    f32x2 sA = {0.f, 0.f}, sB = {0.f, 0.f};
    int c0 = 0, c1 = 0, c2 = 0, c3 = 0;   // per-lane counts (v_addc via vcc)
    #pragma unroll 4
    for (int k = 0; k < total; ++k) {
        const float2 ct = ci_s[k];        // ds_read_b64 broadcast
        const float  li = ct.x, te = ct.y;
        const f32x2  li2 = { li, li };
        f32x2 xA = li2 + nljpA;           // v_pk_add_f32
        f32x2 xB = li2 + nljpB;
        float h0 = fminf(xA.x, 0.f);      // -hinge
        float h1 = fminf(xA.y, 0.f);
        float h2 = fminf(xB.x, 0.f);
        float h3 = fminf(xB.y, 0.f);
        const bool m0 = te < tj0;
        const bool m1 = te < tj1;
        const bool m2 = te < tj2;
        const bool m3 = te < tj3;
        f32x2 hmA = { m0 ? h0 : 0.f, m1 ? h1 : 0.f };
        f32x2 hmB = { m2 ? h2 : 0.f, m3 ? h3 : 0.f };
        sA += hmA * hmA;                  // v_pk_fma_f32
        sB += hmB * hmB;
        c0 += (int)m0;
        c1 += (int)m1;
        c2 += (int)m2;
        c3 += (int)m3;
    }

    float sum = (sA.x + sA.y) + (sB.x + sB.y);
    int   cnt = (c0 + c1) + (c2 + c3);
    for (int off = 32; off > 0; off >>= 1) {
        sum += __shfl_down(sum, off, 64);
        cnt += __shfl_down(cnt, off, 64);
    }

    const int lane = threadIdx.x & 63;
    const int wid  = threadIdx.x >> 6;
    if (lane == 0) { wsum[wid] = sum; wcnt[wid] = cnt; }
    __syncthreads();
    if (threadIdx.x == 0) {
        float s = 0.f; int c = 0;
        #pragma unroll
        for (int w = 0; w < BLK / 64; ++w) { s += wsum[w]; c += wcnt[w]; }
        part[blockIdx.x] = make_uint2(__float_as_uint(s), (unsigned)c);
    }
}

__global__ __launch_bounds__(64) void svm_final(
        const uint2* __restrict__ part,
        float* __restrict__ out) {
    float s = 0.f;
    int   c = 0;
    #pragma unroll
    for (int t = (int)threadIdx.x; t < GRID; t += 64) {    // fixed order
        const uint2 p = part[t];
        s += __uint_as_float(p.x);
        c += (int)p.y;
    }
    for (int off = 32; off > 0; off >>= 1) {
        s += __shfl_down(s, off, 64);
        c += __shfl_down(c, off, 64);
    }
    if (threadIdx.x == 0)
        out[0] = s / (float)(c > 0 ? c : 1);
}

extern "C" void kernel_launch(void* const* d_in, const int* in_sizes, int n_in,
                              void* d_out, int out_size, void* d_ws, size_t ws_size,
                              hipStream_t stream) {
    const float* logit = (const float*)d_in[0];   // (N,1) f32
    const float* st    = (const float*)d_in[1];   // (N,2) f32

    uint2* part = (uint2*)d_ws;                   // [GRID] = 2 KB

    svm_partial<<<GRID, BLK, 0, stream>>>(logit, st, part);
    svm_final<<<1, 64, 0, stream>>>(part, (float*)d_out);
}